// Round 3
// baseline (452.191 us; speedup 1.0000x reference)
//
#include <hip/hip_runtime.h>
#include <stdint.h>

#define NTOK 4096
#define NH 12
#define HDIM 64
#define DMODEL 768
#define D3 2304

typedef __attribute__((ext_vector_type(8))) __bf16 bf16x8;
typedef __attribute__((ext_vector_type(4))) float f32x4;

#define MFMA(a, b, c) __builtin_amdgcn_mfma_f32_16x16x32_bf16((a), (b), (c), 0, 0, 0)

// round-half-up bf16 (0.5-ulp bound, same as RNE)
__device__ __forceinline__ uint16_t f2bf(float f) {
  uint32_t u = __builtin_bit_cast(uint32_t, f) + 0x8000u;
  return (uint16_t)(u >> 16);
}
// pack two floats -> two bf16 in one dword: 2 adds + 1 v_perm
__device__ __forceinline__ uint32_t packrd(float a, float b) {
  uint32_t ua = __builtin_bit_cast(uint32_t, a) + 0x8000u;
  uint32_t ub = __builtin_bit_cast(uint32_t, b) + 0x8000u;
  return __builtin_amdgcn_perm(ub, ua, 0x07060302u);
}
__device__ __forceinline__ float bf2f(uint16_t u) {
  uint32_t v = ((uint32_t)u) << 16;
  return __builtin_bit_cast(float, v);
}
// async global->LDS, 16B per lane; lds must be wave-uniform base (+ lane*16 implicit)
__device__ __forceinline__ void gld_lds16(const uint16_t* g, uint16_t* l) {
  __builtin_amdgcn_global_load_lds((const __attribute__((address_space(1))) void*)g,
                                   (__attribute__((address_space(3))) void*)l, 16, 0, 0);
}

// ---------------- cast hidden fp32 -> bf16 ----------------
__global__ void va_cast_bf16(const float* __restrict__ in, uint16_t* __restrict__ out, int n4) {
  int i = blockIdx.x * 256 + threadIdx.x;
  if (i >= n4) return;
  float4 v = ((const float4*)in)[i];
  ((uint2*)out)[i] = make_uint2(packrd(v.x, v.y), packrd(v.z, v.w));
}

// ---------------- transpose + cast: W[K][N] fp32 -> Wt[N][K] bf16 ----------------
__global__ void va_transpose_cast(const float* __restrict__ W, uint16_t* __restrict__ Wt,
                                  int K, int Ncols) {
  __shared__ uint16_t tile[32][36];
  const int t = threadIdx.x;
  const int k0 = blockIdx.y * 32, n0 = blockIdx.x * 32;
  {
    int i = t >> 3, j = (t & 7) * 4;
    float4 v = *(const float4*)(W + (size_t)(k0 + i) * Ncols + n0 + j);
    tile[i][j + 0] = f2bf(v.x);
    tile[i][j + 1] = f2bf(v.y);
    tile[i][j + 2] = f2bf(v.z);
    tile[i][j + 3] = f2bf(v.w);
  }
  __syncthreads();
  {
    int c = t >> 3, kk = (t & 7) * 4;
    uint32_t lo = (uint32_t)tile[kk + 0][c] | ((uint32_t)tile[kk + 1][c] << 16);
    uint32_t hi = (uint32_t)tile[kk + 2][c] | ((uint32_t)tile[kk + 3][c] << 16);
    *(uint2*)(Wt + (size_t)(n0 + c) * K + k0 + kk) = make_uint2(lo, hi);
  }
}

// ---------------- m97-style GEMM: C = A[M][K] @ Bt[N][K]^T + bias ----------------
// 128x128 tile, BK=32, global_load_lds width-16 staging into unpadded LDS.
template <int OUT_BF16>
__global__ __launch_bounds__(256) void va_gemm97(const uint16_t* __restrict__ A,
                                                 const uint16_t* __restrict__ Bt,
                                                 const float* __restrict__ bias, void* Cout,
                                                 int M, int Nc, int K) {
  __shared__ uint16_t As[128 * 32];
  __shared__ uint16_t Bs[128 * 32];
  const int t = threadIdx.x;
  const int w = t >> 6, ln = t & 63, quad = ln >> 4, l15 = ln & 15;
  const int m0 = blockIdx.y * 128, n0 = blockIdx.x * 128;
  const int wm = (w & 1) * 64, wn = (w >> 1) * 64;
  const int srow = t >> 2, scol = (t & 3) * 8;  // staging: row t>>2, 8-elem chunk t&3
  f32x4 acc[4][4] = {};
  for (int kk = 0; kk < K; kk += 32) {
#pragma unroll
    for (int p = 0; p < 2; ++p) {
      gld_lds16(A + (size_t)(m0 + p * 64 + srow) * K + kk + scol, As + (p * 64 + w * 16) * 32);
      gld_lds16(Bt + (size_t)(n0 + p * 64 + srow) * K + kk + scol, Bs + (p * 64 + w * 16) * 32);
    }
    __syncthreads();
    bf16x8 af[4], bfr[4];
#pragma unroll
    for (int i = 0; i < 4; ++i) {
      af[i] = *(const bf16x8*)(As + (wm + i * 16 + l15) * 32 + quad * 8);
      bfr[i] = *(const bf16x8*)(Bs + (wn + i * 16 + l15) * 32 + quad * 8);
    }
#pragma unroll
    for (int i = 0; i < 4; ++i)
#pragma unroll
      for (int j = 0; j < 4; ++j) acc[i][j] = MFMA(af[i], bfr[j], acc[i][j]);
    __syncthreads();
  }
#pragma unroll
  for (int i = 0; i < 4; ++i) {
    int row = m0 + wm + i * 16 + quad * 4;
#pragma unroll
    for (int j = 0; j < 4; ++j) {
      int col = n0 + wn + j * 16 + l15;
      float b = bias[col];
      if (OUT_BF16) {
        uint16_t* C = (uint16_t*)Cout;
#pragma unroll
        for (int rg = 0; rg < 4; ++rg) C[(size_t)(row + rg) * Nc + col] = f2bf(acc[i][j][rg] + b);
      } else {
        float* C = (float*)Cout;
#pragma unroll
        for (int rg = 0; rg < 4; ++rg) C[(size_t)(row + rg) * Nc + col] = acc[i][j][rg] + b;
      }
    }
  }
}

// ---------------- RoPE + layout split (bf16 in) ----------------
// qkvb bf16 [N][2304] -> Q[h][n][64] (x SCALE*log2e), K[h][n][64], Vt[h][64][n] bf16
// block: 64 tokens x 4 d-quarters
__global__ void va_rope_split(const uint16_t* __restrict__ qkvb, const float* __restrict__ cosb,
                              const float* __restrict__ sinb, uint16_t* __restrict__ Qg,
                              uint16_t* __restrict__ Kg, uint16_t* __restrict__ Vtg) {
  const int h = blockIdx.y;
  const int lane = threadIdx.x & 63;
  const int c = threadIdx.x >> 6;  // quarter
  const int n = blockIdx.x * 64 + lane;
  const uint16_t* base = qkvb + (size_t)n * D3 + h * HDIM;
  const float QS = 0.125f * 1.4426950408889634f;
  float c0[8], s0[8], c1[8], s1[8];
  *(float4*)(c0) = *(const float4*)(cosb + (size_t)n * HDIM + c * 8);
  *(float4*)(c0 + 4) = *(const float4*)(cosb + (size_t)n * HDIM + c * 8 + 4);
  *(float4*)(s0) = *(const float4*)(sinb + (size_t)n * HDIM + c * 8);
  *(float4*)(s0 + 4) = *(const float4*)(sinb + (size_t)n * HDIM + c * 8 + 4);
  *(float4*)(c1) = *(const float4*)(cosb + (size_t)n * HDIM + c * 8 + 32);
  *(float4*)(c1 + 4) = *(const float4*)(cosb + (size_t)n * HDIM + c * 8 + 36);
  *(float4*)(s1) = *(const float4*)(sinb + (size_t)n * HDIM + c * 8 + 32);
  *(float4*)(s1 + 4) = *(const float4*)(sinb + (size_t)n * HDIM + c * 8 + 36);
#pragma unroll
  for (int mtx = 0; mtx < 2; ++mtx) {
    const uint16_t* src = base + mtx * DMODEL;
    uint16_t* dst = (mtx ? Kg : Qg) + ((size_t)h * NTOK + n) * HDIM;
    const float sc = mtx ? 1.0f : QS;
    uint16_t lo[8], hi[8];
    *(uint4*)lo = *(const uint4*)(src + c * 8);
    *(uint4*)hi = *(const uint4*)(src + c * 8 + 32);
    uint32_t outlo[4], outhi[4];
#pragma unroll
    for (int j = 0; j < 8; j += 2) {
      float x0 = bf2f(lo[j]), x1 = bf2f(lo[j + 1]);
      float y0 = bf2f(hi[j]), y1 = bf2f(hi[j + 1]);
      float a0 = (x0 * c0[j] - y0 * s0[j]) * sc;
      float a1 = (x1 * c0[j + 1] - y1 * s0[j + 1]) * sc;
      float b0 = (y0 * c1[j] + x0 * s1[j]) * sc;
      float b1 = (y1 * c1[j + 1] + x1 * s1[j + 1]) * sc;
      outlo[j >> 1] = packrd(a0, a1);
      outhi[j >> 1] = packrd(b0, b1);
    }
    *(uint4*)(dst + c * 8) = *(uint4*)outlo;
    *(uint4*)(dst + c * 8 + 32) = *(uint4*)outhi;
  }
  // V pass-through transpose: d in [c*16, c*16+16)
  uint16_t vv[16];
  *(uint4*)(vv) = *(const uint4*)(base + 2 * DMODEL + c * 16);
  *(uint4*)(vv + 8) = *(const uint4*)(base + 2 * DMODEL + c * 16 + 8);
#pragma unroll
  for (int j = 0; j < 16; ++j)
    Vtg[((size_t)h * HDIM + c * 16 + j) * NTOK + n] = vv[j];
}

// ---------------- Flash attention v3: 4-way key split, no online max ----------------
// Grid: x = qb(32) | ks(4)<<5, y = head. 4 waves x 32q; 16 iters of 64-key tiles.
// p = exp2(score) directly (scores bounded ~ +-30 in exp2 domain -> fp32 safe).
__global__ __launch_bounds__(256, 5) void va_flash3(const uint16_t* __restrict__ Qg,
                                                    const uint16_t* __restrict__ Kg,
                                                    const uint16_t* __restrict__ Vtg,
                                                    uint16_t* __restrict__ Opb,
                                                    float* __restrict__ Lp) {
  __shared__ uint16_t Ks0[64 * 40];
  __shared__ uint16_t Ks1[64 * 40];
  __shared__ uint16_t Ps[4][2][16 * 40];  // per wave, per key-half, reused across s
  const int t = threadIdx.x;
  const int w = t >> 6, ln = t & 63, quad = ln >> 4, l15 = ln & 15;
  const int h = blockIdx.y;
  const int qb = blockIdx.x & 31, ks = blockIdx.x >> 5;
  const int q0 = qb * 128, key0 = ks * 1024;

  bf16x8 qf[2][2];
#pragma unroll
  for (int s = 0; s < 2; ++s)
#pragma unroll
    for (int c = 0; c < 2; ++c)
      qf[s][c] = *(const bf16x8*)(Qg + ((size_t)h * NTOK + q0 + w * 32 + s * 16 + l15) * HDIM +
                                  c * 32 + quad * 8);
  f32x4 o[2][4] = {};
  float lpart[2] = {0.f, 0.f};
  const int kr = t >> 2, kc = t & 3;
  const uint16_t* Kbase = Kg + ((size_t)h * NTOK + key0) * HDIM;
  bf16x8 kpre0 = *(const bf16x8*)(Kbase + (size_t)kr * HDIM + kc * 8);
  bf16x8 kpre1 = *(const bf16x8*)(Kbase + (size_t)kr * HDIM + kc * 8 + 32);

  for (int kt = 0; kt < 16; ++kt) {
    *(bf16x8*)(Ks0 + kr * 40 + kc * 8) = kpre0;
    *(bf16x8*)(Ks1 + kr * 40 + kc * 8) = kpre1;
    __syncthreads();
    if (kt < 15) {
      const uint16_t* kb = Kbase + (size_t)((kt + 1) * 64 + kr) * HDIM;
      kpre0 = *(const bf16x8*)(kb + kc * 8);
      kpre1 = *(const bf16x8*)(kb + kc * 8 + 32);
    }
    f32x4 st[2][4];
#pragma unroll
    for (int mt = 0; mt < 4; ++mt) {
      bf16x8 ka0 = *(const bf16x8*)(Ks0 + (mt * 16 + l15) * 40 + quad * 8);
      bf16x8 ka1 = *(const bf16x8*)(Ks1 + (mt * 16 + l15) * 40 + quad * 8);
#pragma unroll
      for (int s = 0; s < 2; ++s) {
        f32x4 z = {};
        z = MFMA(ka0, qf[s][0], z);
        st[s][mt] = MFMA(ka1, qf[s][1], z);
      }
    }
    // V fragments direct from global (L2-resident)
    bf16x8 vf[4][2];
    const uint16_t* Vb = Vtg + (size_t)h * HDIM * NTOK + key0 + kt * 64;
#pragma unroll
    for (int dt = 0; dt < 4; ++dt)
#pragma unroll
      for (int kx = 0; kx < 2; ++kx)
        vf[dt][kx] = *(const bf16x8*)(Vb + (size_t)(dt * 16 + l15) * NTOK + kx * 32 + quad * 8);
#pragma unroll
    for (int s = 0; s < 2; ++s) {
      float p[16];
      float ls = 0.f;
#pragma unroll
      for (int mt = 0; mt < 4; ++mt)
#pragma unroll
        for (int e = 0; e < 4; ++e) {
          float pe = __builtin_amdgcn_exp2f(st[s][mt][e]);
          p[mt * 4 + e] = pe;
          ls += pe;
        }
      lpart[s] += ls;
#pragma unroll
      for (int mt = 0; mt < 4; ++mt)
        *(uint2*)(&Ps[w][mt >> 1][0] + l15 * 40 + (mt & 1) * 16 + quad * 4) =
            make_uint2(packrd(p[mt * 4 + 0], p[mt * 4 + 1]),
                       packrd(p[mt * 4 + 2], p[mt * 4 + 3]));
      __builtin_amdgcn_sched_barrier(0);  // DS write->read order (intra-wave P exchange)
      bf16x8 pf0 = *(const bf16x8*)(&Ps[w][0][0] + l15 * 40 + quad * 8);
      bf16x8 pf1 = *(const bf16x8*)(&Ps[w][1][0] + l15 * 40 + quad * 8);
#pragma unroll
      for (int dt = 0; dt < 4; ++dt) {
        o[s][dt] = MFMA(vf[dt][0], pf0, o[s][dt]);
        o[s][dt] = MFMA(vf[dt][1], pf1, o[s][dt]);
      }
    }
    __syncthreads();
  }
  // epilogue: store unnormalized O^T bf16 + per-query l (fp32)
  uint16_t* ob = Opb + ((size_t)(ks * NH + h) * HDIM) * NTOK;
#pragma unroll
  for (int s = 0; s < 2; ++s) {
    int q = q0 + w * 32 + s * 16 + l15;
    float l = lpart[s];
    l += __shfl_xor(l, 16, 64);
    l += __shfl_xor(l, 32, 64);
#pragma unroll
    for (int dt = 0; dt < 4; ++dt)
#pragma unroll
      for (int rg = 0; rg < 4; ++rg)
        ob[(size_t)(dt * 16 + quad * 4 + rg) * NTOK + q] = f2bf(o[s][dt][rg]);
    if (quad == 0) Lp[(size_t)(ks * NH + h) * NTOK + q] = l;
  }
}

// ---------------- combine 4 key-splits, normalize, write bf16 [n][h*64+d] ----------------
__global__ __launch_bounds__(256) void va_combine4(const uint16_t* __restrict__ Opb,
                                                   const float* __restrict__ Lp,
                                                   uint16_t* __restrict__ Ob) {
  __shared__ uint16_t T[64][72];
  const int h = blockIdx.y;
  const int n0 = blockIdx.x * 64;
  const int t = threadIdx.x;
  const int lane = t & 63, c = t >> 6;
  const int n = n0 + lane;
  float lsum = 0.f;
#pragma unroll
  for (int s = 0; s < 4; ++s) lsum += Lp[(size_t)(s * NH + h) * NTOK + n];
  const float inv = 1.0f / lsum;
#pragma unroll
  for (int j = 0; j < 16; j += 2) {
    int d = c * 16 + j;
    float r0 = 0.f, r1 = 0.f;
#pragma unroll
    for (int s = 0; s < 4; ++s) {
      const uint16_t* p = Opb + ((size_t)(s * NH + h) * HDIM + d) * NTOK + n;
      r0 += bf2f(p[0]);
      r1 += bf2f(p[NTOK]);
    }
    *(uint32_t*)(&T[lane][d]) = packrd(r0 * inv, r1 * inv);
  }
  __syncthreads();
  const int row = t >> 2, ch = t & 3;
  uint4 a = *(const uint4*)(&T[row][ch * 16]);
  uint4 b = *(const uint4*)(&T[row][ch * 16 + 8]);
  uint16_t* dst = Ob + (size_t)(n0 + row) * DMODEL + h * HDIM + ch * 16;
  *(uint4*)dst = a;
  *(uint4*)(dst + 8) = b;
}

extern "C" void kernel_launch(void* const* d_in, const int* in_sizes, int n_in, void* d_out,
                              int out_size, void* d_ws, size_t ws_size, hipStream_t stream) {
  (void)in_sizes; (void)n_in; (void)out_size; (void)ws_size;
  const float* hidden = (const float*)d_in[0];
  const float* cosb = (const float*)d_in[1];
  const float* sinb = (const float*)d_in[2];
  const float* qkv_w = (const float*)d_in[3];
  const float* qkv_b = (const float*)d_in[4];
  const float* proj_w = (const float*)d_in[5];
  const float* proj_b = (const float*)d_in[6];
  float* out = (float*)d_out;

  char* ws = (char*)d_ws;
  size_t off = 0;
  auto alloc = [&](size_t bytes) {
    void* p = ws + off;
    off += (bytes + 255) & ~(size_t)255;
    return p;
  };
  uint16_t* Abf = (uint16_t*)alloc((size_t)NTOK * DMODEL * 2);
  uint16_t* Wqt = (uint16_t*)alloc((size_t)D3 * DMODEL * 2);
  uint16_t* Wpt = (uint16_t*)alloc((size_t)DMODEL * DMODEL * 2);
  uint16_t* qkvb = (uint16_t*)alloc((size_t)NTOK * D3 * 2);
  uint16_t* Qb = (uint16_t*)alloc((size_t)NH * NTOK * HDIM * 2);
  uint16_t* Kb = (uint16_t*)alloc((size_t)NH * NTOK * HDIM * 2);
  uint16_t* Vtb = (uint16_t*)alloc((size_t)NH * NTOK * HDIM * 2);
  uint16_t* Ob = (uint16_t*)alloc((size_t)NTOK * DMODEL * 2);
  uint16_t* Opb = (uint16_t*)alloc((size_t)4 * NH * HDIM * NTOK * 2);
  float* Lp = (float*)alloc((size_t)4 * NH * NTOK * 4);
  // total ws ~82 MB

  va_cast_bf16<<<(NTOK * DMODEL / 4 + 255) / 256, 256, 0, stream>>>(hidden, Abf,
                                                                    NTOK * DMODEL / 4);
  va_transpose_cast<<<dim3(D3 / 32, DMODEL / 32), 256, 0, stream>>>(qkv_w, Wqt, DMODEL, D3);
  va_transpose_cast<<<dim3(DMODEL / 32, DMODEL / 32), 256, 0, stream>>>(proj_w, Wpt, DMODEL,
                                                                        DMODEL);
  va_gemm97<1><<<dim3(D3 / 128, NTOK / 128), 256, 0, stream>>>(Abf, Wqt, qkv_b, qkvb, NTOK, D3,
                                                               DMODEL);
  va_rope_split<<<dim3(NTOK / 64, NH), 256, 0, stream>>>(qkvb, cosb, sinb, Qb, Kb, Vtb);
  va_flash3<<<dim3(128, NH), 256, 0, stream>>>(Qb, Kb, Vtb, Opb, Lp);
  va_combine4<<<dim3(NTOK / 64, NH), 256, 0, stream>>>(Opb, Lp, Ob);
  va_gemm97<0><<<dim3(DMODEL / 128, NTOK / 128), 256, 0, stream>>>(Ob, Wpt, proj_b, out, NTOK,
                                                                   DMODEL, DMODEL);
}

// Round 4
// 261.071 us; speedup vs baseline: 1.7321x; 1.7321x over previous
//
#include <hip/hip_runtime.h>
#include <stdint.h>

#define NTOK 4096
#define NH 12
#define HDIM 64
#define DMODEL 768
#define D3 2304

typedef __attribute__((ext_vector_type(8))) __bf16 bf16x8;
typedef __attribute__((ext_vector_type(4))) float f32x4;

#define MFMA(a, b, c) __builtin_amdgcn_mfma_f32_16x16x32_bf16((a), (b), (c), 0, 0, 0)

// round-half-up bf16 (0.5-ulp bound, same as RNE)
__device__ __forceinline__ uint16_t f2bf(float f) {
  uint32_t u = __builtin_bit_cast(uint32_t, f) + 0x8000u;
  return (uint16_t)(u >> 16);
}
// pack two floats -> two bf16 in one dword: 2 adds + 1 v_perm
__device__ __forceinline__ uint32_t packrd(float a, float b) {
  uint32_t ua = __builtin_bit_cast(uint32_t, a) + 0x8000u;
  uint32_t ub = __builtin_bit_cast(uint32_t, b) + 0x8000u;
  return __builtin_amdgcn_perm(ub, ua, 0x07060302u);
}
__device__ __forceinline__ float bf2f(uint16_t u) {
  uint32_t v = ((uint32_t)u) << 16;
  return __builtin_bit_cast(float, v);
}
// async global->LDS, 16B per lane; lds dest = wave-uniform base + lane*16
__device__ __forceinline__ void gld_lds16(const uint16_t* g, uint16_t* l) {
  __builtin_amdgcn_global_load_lds((const __attribute__((address_space(1))) void*)g,
                                   (__attribute__((address_space(3))) void*)l, 16, 0, 0);
}

// ---------------- cast hidden fp32 -> bf16 ----------------
__global__ void va_cast_bf16(const float* __restrict__ in, uint16_t* __restrict__ out, int n4) {
  int i = blockIdx.x * 256 + threadIdx.x;
  if (i >= n4) return;
  float4 v = ((const float4*)in)[i];
  ((uint2*)out)[i] = make_uint2(packrd(v.x, v.y), packrd(v.z, v.w));
}

// ---------------- transpose + cast: W[K][N] fp32 -> Wt[N][K] bf16 ----------------
__global__ void va_transpose_cast(const float* __restrict__ W, uint16_t* __restrict__ Wt,
                                  int K, int Ncols) {
  __shared__ uint16_t tile[32][36];
  const int t = threadIdx.x;
  const int k0 = blockIdx.y * 32, n0 = blockIdx.x * 32;
  {
    int i = t >> 3, j = (t & 7) * 4;
    float4 v = *(const float4*)(W + (size_t)(k0 + i) * Ncols + n0 + j);
    tile[i][j + 0] = f2bf(v.x);
    tile[i][j + 1] = f2bf(v.y);
    tile[i][j + 2] = f2bf(v.z);
    tile[i][j + 3] = f2bf(v.w);
  }
  __syncthreads();
  {
    int c = t >> 3, kk = (t & 7) * 4;
    uint32_t lo = (uint32_t)tile[kk + 0][c] | ((uint32_t)tile[kk + 1][c] << 16);
    uint32_t hi = (uint32_t)tile[kk + 2][c] | ((uint32_t)tile[kk + 3][c] << 16);
    *(uint2*)(Wt + (size_t)(n0 + c) * K + k0 + kk) = make_uint2(lo, hi);
  }
}

// ---------------- m97-style GEMM: C = A[M][K] @ Bt[N][K]^T + bias ----------------
template <int OUT_BF16>
__global__ __launch_bounds__(256) void va_gemm97(const uint16_t* __restrict__ A,
                                                 const uint16_t* __restrict__ Bt,
                                                 const float* __restrict__ bias, void* Cout,
                                                 int M, int Nc, int K) {
  __shared__ uint16_t As[128 * 32];
  __shared__ uint16_t Bs[128 * 32];
  const int t = threadIdx.x;
  const int w = t >> 6, ln = t & 63, quad = ln >> 4, l15 = ln & 15;
  const int m0 = blockIdx.y * 128, n0 = blockIdx.x * 128;
  const int wm = (w & 1) * 64, wn = (w >> 1) * 64;
  const int srow = t >> 2, scol = (t & 3) * 8;
  f32x4 acc[4][4] = {};
  for (int kk = 0; kk < K; kk += 32) {
#pragma unroll
    for (int p = 0; p < 2; ++p) {
      gld_lds16(A + (size_t)(m0 + p * 64 + srow) * K + kk + scol, As + (p * 64 + w * 16) * 32);
      gld_lds16(Bt + (size_t)(n0 + p * 64 + srow) * K + kk + scol, Bs + (p * 64 + w * 16) * 32);
    }
    __syncthreads();
    bf16x8 af[4], bfr[4];
#pragma unroll
    for (int i = 0; i < 4; ++i) {
      af[i] = *(const bf16x8*)(As + (wm + i * 16 + l15) * 32 + quad * 8);
      bfr[i] = *(const bf16x8*)(Bs + (wn + i * 16 + l15) * 32 + quad * 8);
    }
#pragma unroll
    for (int i = 0; i < 4; ++i)
#pragma unroll
      for (int j = 0; j < 4; ++j) acc[i][j] = MFMA(af[i], bfr[j], acc[i][j]);
    __syncthreads();
  }
#pragma unroll
  for (int i = 0; i < 4; ++i) {
    int row = m0 + wm + i * 16 + quad * 4;
#pragma unroll
    for (int j = 0; j < 4; ++j) {
      int col = n0 + wn + j * 16 + l15;
      float b = bias[col];
      if (OUT_BF16) {
        uint16_t* C = (uint16_t*)Cout;
#pragma unroll
        for (int rg = 0; rg < 4; ++rg) C[(size_t)(row + rg) * Nc + col] = f2bf(acc[i][j][rg] + b);
      } else {
        float* C = (float*)Cout;
#pragma unroll
        for (int rg = 0; rg < 4; ++rg) C[(size_t)(row + rg) * Nc + col] = acc[i][j][rg] + b;
      }
    }
  }
}

// ---------------- RoPE + layout split (bf16 in) ----------------
__global__ void va_rope_split(const uint16_t* __restrict__ qkvb, const float* __restrict__ cosb,
                              const float* __restrict__ sinb, uint16_t* __restrict__ Qg,
                              uint16_t* __restrict__ Kg, uint16_t* __restrict__ Vtg) {
  const int h = blockIdx.y;
  const int lane = threadIdx.x & 63;
  const int c = threadIdx.x >> 6;
  const int n = blockIdx.x * 64 + lane;
  const uint16_t* base = qkvb + (size_t)n * D3 + h * HDIM;
  const float QS = 0.125f * 1.4426950408889634f;
  float c0[8], s0[8], c1[8], s1[8];
  *(float4*)(c0) = *(const float4*)(cosb + (size_t)n * HDIM + c * 8);
  *(float4*)(c0 + 4) = *(const float4*)(cosb + (size_t)n * HDIM + c * 8 + 4);
  *(float4*)(s0) = *(const float4*)(sinb + (size_t)n * HDIM + c * 8);
  *(float4*)(s0 + 4) = *(const float4*)(sinb + (size_t)n * HDIM + c * 8 + 4);
  *(float4*)(c1) = *(const float4*)(cosb + (size_t)n * HDIM + c * 8 + 32);
  *(float4*)(c1 + 4) = *(const float4*)(cosb + (size_t)n * HDIM + c * 8 + 36);
  *(float4*)(s1) = *(const float4*)(sinb + (size_t)n * HDIM + c * 8 + 32);
  *(float4*)(s1 + 4) = *(const float4*)(sinb + (size_t)n * HDIM + c * 8 + 36);
#pragma unroll
  for (int mtx = 0; mtx < 2; ++mtx) {
    const uint16_t* src = base + mtx * DMODEL;
    uint16_t* dst = (mtx ? Kg : Qg) + ((size_t)h * NTOK + n) * HDIM;
    const float sc = mtx ? 1.0f : QS;
    uint16_t lo[8], hi[8];
    *(uint4*)lo = *(const uint4*)(src + c * 8);
    *(uint4*)hi = *(const uint4*)(src + c * 8 + 32);
    uint32_t outlo[4], outhi[4];
#pragma unroll
    for (int j = 0; j < 8; j += 2) {
      float x0 = bf2f(lo[j]), x1 = bf2f(lo[j + 1]);
      float y0 = bf2f(hi[j]), y1 = bf2f(hi[j + 1]);
      float a0 = (x0 * c0[j] - y0 * s0[j]) * sc;
      float a1 = (x1 * c0[j + 1] - y1 * s0[j + 1]) * sc;
      float b0 = (y0 * c1[j] + x0 * s1[j]) * sc;
      float b1 = (y1 * c1[j + 1] + x1 * s1[j + 1]) * sc;
      outlo[j >> 1] = packrd(a0, a1);
      outhi[j >> 1] = packrd(b0, b1);
    }
    *(uint4*)(dst + c * 8) = *(uint4*)outlo;
    *(uint4*)(dst + c * 8 + 32) = *(uint4*)outhi;
  }
  uint16_t vv[16];
  *(uint4*)(vv) = *(const uint4*)(base + 2 * DMODEL + c * 16);
  *(uint4*)(vv + 8) = *(const uint4*)(base + 2 * DMODEL + c * 16 + 8);
#pragma unroll
  for (int j = 0; j < 16; ++j)
    Vtg[((size_t)h * HDIM + c * 16 + j) * NTOK + n] = vv[j];
}

// ---------------- Flash attention v4: no online max, async double-buffered K ----------------
// Grid: x = qb(32) | ks(4)<<5, y = head. 4 waves x 32q; 16 iters of 64-key tiles.
// K staged via global_load_lds (width 16) into double-buffered unpadded LDS; one barrier/iter.
__global__ __launch_bounds__(256, 4) void va_flash4(const uint16_t* __restrict__ Qg,
                                                    const uint16_t* __restrict__ Kg,
                                                    const uint16_t* __restrict__ Vtg,
                                                    uint16_t* __restrict__ Opb,
                                                    float* __restrict__ Lp) {
  __shared__ uint16_t Ks[2][2][64 * 32];  // [dbuf][col-half][64 keys x 32 d]
  __shared__ uint16_t Ps[4][2][16 * 40];  // per wave, per key-half, reused across s
  const int t = threadIdx.x;
  const int w = t >> 6, ln = t & 63, quad = ln >> 4, l15 = ln & 15;
  const int h = blockIdx.y;
  const int qb = blockIdx.x & 31, ks = blockIdx.x >> 5;
  const int q0 = qb * 128, key0 = ks * 1024;

  bf16x8 qf[2][2];
#pragma unroll
  for (int s = 0; s < 2; ++s)
#pragma unroll
    for (int c = 0; c < 2; ++c)
      qf[s][c] = *(const bf16x8*)(Qg + ((size_t)h * NTOK + q0 + w * 32 + s * 16 + l15) * HDIM +
                                  c * 32 + quad * 8);
  f32x4 o[2][4] = {};
  float lpart[2] = {0.f, 0.f};
  const uint16_t* Kbase =
      Kg + ((size_t)h * NTOK + key0) * HDIM + (size_t)(w * 16 + (ln >> 2)) * HDIM + (ln & 3) * 8;
  // stage tile 0
  gld_lds16(Kbase, &Ks[0][0][w * 16 * 32]);
  gld_lds16(Kbase + 32, &Ks[0][1][w * 16 * 32]);

  for (int kt = 0; kt < 16; ++kt) {
    __syncthreads();  // staging of Ks[kt&1] complete; prior reads of Ks[(kt+1)&1] done
    const int cur = kt & 1;
    if (kt < 15) {
      const uint16_t* kb = Kbase + (size_t)((kt + 1) * 64) * HDIM;
      gld_lds16(kb, &Ks[cur ^ 1][0][w * 16 * 32]);
      gld_lds16(kb + 32, &Ks[cur ^ 1][1][w * 16 * 32]);
    }
    f32x4 st[2][4];
#pragma unroll
    for (int mt = 0; mt < 4; ++mt) {
      bf16x8 ka0 = *(const bf16x8*)(&Ks[cur][0][(mt * 16 + l15) * 32 + quad * 8]);
      bf16x8 ka1 = *(const bf16x8*)(&Ks[cur][1][(mt * 16 + l15) * 32 + quad * 8]);
#pragma unroll
      for (int s = 0; s < 2; ++s) {
        f32x4 z = {};
        z = MFMA(ka0, qf[s][0], z);
        st[s][mt] = MFMA(ka1, qf[s][1], z);
      }
    }
    // V fragments direct from global (L2-resident)
    bf16x8 vf[4][2];
    const uint16_t* Vb = Vtg + (size_t)h * HDIM * NTOK + key0 + kt * 64;
#pragma unroll
    for (int dt = 0; dt < 4; ++dt)
#pragma unroll
      for (int kx = 0; kx < 2; ++kx)
        vf[dt][kx] = *(const bf16x8*)(Vb + (size_t)(dt * 16 + l15) * NTOK + kx * 32 + quad * 8);
#pragma unroll
    for (int s = 0; s < 2; ++s) {
      float ls = 0.f;
#pragma unroll
      for (int mt = 0; mt < 4; ++mt) {
        float p0 = __builtin_amdgcn_exp2f(st[s][mt][0]);
        float p1 = __builtin_amdgcn_exp2f(st[s][mt][1]);
        float p2 = __builtin_amdgcn_exp2f(st[s][mt][2]);
        float p3 = __builtin_amdgcn_exp2f(st[s][mt][3]);
        ls += (p0 + p1) + (p2 + p3);
        *(uint2*)(&Ps[w][mt >> 1][0] + l15 * 40 + (mt & 1) * 16 + quad * 4) =
            make_uint2(packrd(p0, p1), packrd(p2, p3));
      }
      lpart[s] += ls;
      __builtin_amdgcn_sched_barrier(0);  // DS write->read order (intra-wave P exchange)
      bf16x8 pf0 = *(const bf16x8*)(&Ps[w][0][0] + l15 * 40 + quad * 8);
      bf16x8 pf1 = *(const bf16x8*)(&Ps[w][1][0] + l15 * 40 + quad * 8);
      __builtin_amdgcn_sched_barrier(0);  // P reads before next s overwrites Ps
#pragma unroll
      for (int dt = 0; dt < 4; ++dt) {
        o[s][dt] = MFMA(vf[dt][0], pf0, o[s][dt]);
        o[s][dt] = MFMA(vf[dt][1], pf1, o[s][dt]);
      }
    }
  }
  // epilogue: store unnormalized O^T bf16 + per-query l (fp32)
  uint16_t* ob = Opb + ((size_t)(ks * NH + h) * HDIM) * NTOK;
#pragma unroll
  for (int s = 0; s < 2; ++s) {
    int q = q0 + w * 32 + s * 16 + l15;
    float l = lpart[s];
    l += __shfl_xor(l, 16, 64);
    l += __shfl_xor(l, 32, 64);
#pragma unroll
    for (int dt = 0; dt < 4; ++dt)
#pragma unroll
      for (int rg = 0; rg < 4; ++rg)
        ob[(size_t)(dt * 16 + quad * 4 + rg) * NTOK + q] = f2bf(o[s][dt][rg]);
    if (quad == 0) Lp[(size_t)(ks * NH + h) * NTOK + q] = l;
  }
}

// ---------------- combine 4 key-splits, normalize, write bf16 [n][h*64+d] ----------------
__global__ __launch_bounds__(256) void va_combine4(const uint16_t* __restrict__ Opb,
                                                   const float* __restrict__ Lp,
                                                   uint16_t* __restrict__ Ob) {
  __shared__ uint16_t T[64][72];
  const int h = blockIdx.y;
  const int n0 = blockIdx.x * 64;
  const int t = threadIdx.x;
  const int lane = t & 63, c = t >> 6;
  const int n = n0 + lane;
  float lsum = 0.f;
#pragma unroll
  for (int s = 0; s < 4; ++s) lsum += Lp[(size_t)(s * NH + h) * NTOK + n];
  const float inv = 1.0f / lsum;
#pragma unroll
  for (int j = 0; j < 16; j += 2) {
    int d = c * 16 + j;
    float r0 = 0.f, r1 = 0.f;
#pragma unroll
    for (int s = 0; s < 4; ++s) {
      const uint16_t* p = Opb + ((size_t)(s * NH + h) * HDIM + d) * NTOK + n;
      r0 += bf2f(p[0]);
      r1 += bf2f(p[NTOK]);
    }
    *(uint32_t*)(&T[lane][d]) = packrd(r0 * inv, r1 * inv);
  }
  __syncthreads();
  const int row = t >> 2, ch = t & 3;
  uint4 a = *(const uint4*)(&T[row][ch * 16]);
  uint4 b = *(const uint4*)(&T[row][ch * 16 + 8]);
  uint16_t* dst = Ob + (size_t)(n0 + row) * DMODEL + h * HDIM + ch * 16;
  *(uint4*)dst = a;
  *(uint4*)(dst + 8) = b;
}

extern "C" void kernel_launch(void* const* d_in, const int* in_sizes, int n_in, void* d_out,
                              int out_size, void* d_ws, size_t ws_size, hipStream_t stream) {
  (void)in_sizes; (void)n_in; (void)out_size; (void)ws_size;
  const float* hidden = (const float*)d_in[0];
  const float* cosb = (const float*)d_in[1];
  const float* sinb = (const float*)d_in[2];
  const float* qkv_w = (const float*)d_in[3];
  const float* qkv_b = (const float*)d_in[4];
  const float* proj_w = (const float*)d_in[5];
  const float* proj_b = (const float*)d_in[6];
  float* out = (float*)d_out;

  char* ws = (char*)d_ws;
  size_t off = 0;
  auto alloc = [&](size_t bytes) {
    void* p = ws + off;
    off += (bytes + 255) & ~(size_t)255;
    return p;
  };
  uint16_t* Abf = (uint16_t*)alloc((size_t)NTOK * DMODEL * 2);
  uint16_t* Wqt = (uint16_t*)alloc((size_t)D3 * DMODEL * 2);
  uint16_t* Wpt = (uint16_t*)alloc((size_t)DMODEL * DMODEL * 2);
  uint16_t* qkvb = (uint16_t*)alloc((size_t)NTOK * D3 * 2);
  uint16_t* Qb = (uint16_t*)alloc((size_t)NH * NTOK * HDIM * 2);
  uint16_t* Kb = (uint16_t*)alloc((size_t)NH * NTOK * HDIM * 2);
  uint16_t* Vtb = (uint16_t*)alloc((size_t)NH * NTOK * HDIM * 2);
  uint16_t* Ob = (uint16_t*)alloc((size_t)NTOK * DMODEL * 2);
  uint16_t* Opb = (uint16_t*)alloc((size_t)4 * NH * HDIM * NTOK * 2);
  float* Lp = (float*)alloc((size_t)4 * NH * NTOK * 4);

  va_cast_bf16<<<(NTOK * DMODEL / 4 + 255) / 256, 256, 0, stream>>>(hidden, Abf,
                                                                    NTOK * DMODEL / 4);
  va_transpose_cast<<<dim3(D3 / 32, DMODEL / 32), 256, 0, stream>>>(qkv_w, Wqt, DMODEL, D3);
  va_transpose_cast<<<dim3(DMODEL / 32, DMODEL / 32), 256, 0, stream>>>(proj_w, Wpt, DMODEL,
                                                                        DMODEL);
  va_gemm97<1><<<dim3(D3 / 128, NTOK / 128), 256, 0, stream>>>(Abf, Wqt, qkv_b, qkvb, NTOK, D3,
                                                               DMODEL);
  va_rope_split<<<dim3(NTOK / 64, NH), 256, 0, stream>>>(qkvb, cosb, sinb, Qb, Kb, Vtb);
  va_flash4<<<dim3(128, NH), 256, 0, stream>>>(Qb, Kb, Vtb, Opb, Lp);
  va_combine4<<<dim3(NTOK / 64, NH), 256, 0, stream>>>(Opb, Lp, Ob);
  va_gemm97<0><<<dim3(DMODEL / 128, NTOK / 128), 256, 0, stream>>>(Ob, Wpt, proj_b, out, NTOK,
                                                                   DMODEL, DMODEL);
}